// Round 11
// baseline (231.750 us; speedup 1.0000x reference)
//
#include <hip/hip_runtime.h>
#include <hip/hip_bf16.h>
#include <math.h>

#define N_NODES 50000
#define N_EDGES 500000
#define AGB (N_NODES / 4)   // 12500 agg blocks (4 nodes/block)

typedef __bf16 bf16x8 __attribute__((ext_vector_type(8)));
typedef float f32x4 __attribute__((ext_vector_type(4)));
typedef unsigned int u32x4 __attribute__((ext_vector_type(4)));

static __device__ __forceinline__ float bf2f_lo(unsigned int v) {
  return __uint_as_float(v << 16);
}
static __device__ __forceinline__ float bf2f_hi(unsigned int v) {
  return __uint_as_float(v & 0xffff0000u);
}
static __device__ __forceinline__ unsigned short f2bf(float f) {
  unsigned int u = __float_as_uint(f);
  return (unsigned short)((u + 0x7fffu + ((u >> 16) & 1u)) >> 16);
}
static __device__ __forceinline__ bf16x8 ld8(const unsigned short* p) {
  u32x4 u = *(const u32x4*)p;
  return __builtin_bit_cast(bf16x8, u);
}

// ---------------------------------------------------------------------------
// Prep: x->bf16, pack W1/W2/W3 to [FO][FI] bf16, zero cnt+fill (contiguous)
// ---------------------------------------------------------------------------
__global__ void prep_kernel(const float* __restrict__ x, unsigned short* __restrict__ xb,
                            const float* __restrict__ W1l, const float* __restrict__ W1r,
                            unsigned short* __restrict__ w1b,
                            const float* __restrict__ W2l, const float* __restrict__ W2r,
                            unsigned short* __restrict__ w2b,
                            const float* __restrict__ W3l, const float* __restrict__ W3r,
                            unsigned short* __restrict__ w3b,
                            int* __restrict__ cntfill) {
  int idx = blockIdx.x * 256 + threadIdx.x;
  if (idx < 1600000) {
    float4 v = ((const float4*)x)[idx];
    ushort4 o;
    o.x = f2bf(v.x); o.y = f2bf(v.y); o.z = f2bf(v.z); o.w = f2bf(v.w);
    ((ushort4*)xb)[idx] = o;
  } else if (idx < 1665536) {
    int i = idx - 1600000;
    int j = i >> 8, k = i & 255;                       // FI=256, kcat FIh=128
    float v = (k < 128) ? W1l[j * 128 + k] : W1r[j * 128 + (k - 128)];
    w1b[i] = f2bf(v);
  } else if (idx < 1731072) {
    int i = idx - 1665536;
    int j = i >> 8, k = i & 255;                       // FI=256, jcat FOh=128
    float v = (j < 128) ? W2l[j * 256 + k] : W2r[(j - 128) * 256 + k];
    w2b[i] = f2bf(v);
  } else if (idx < 1747456) {
    int i = idx - 1731072;
    int j = i >> 7, k = i & 127;                       // FI=128, jcat FOh=64
    float v = (j < 64) ? W3l[j * 128 + k] : W3r[(j - 64) * 128 + k];
    w3b[i] = f2bf(v);
  } else if (idx < 1772456) {
    int i = idx - 1747456;
    ((int4*)cntfill)[i] = make_int4(0, 0, 0, 0);
  }
}

// ---------------------------------------------------------------------------
// CSR build: hist -> chunk sums -> scan_final (inline cross-block offset) -> fill
// ---------------------------------------------------------------------------
__global__ void hist_kernel(const int* __restrict__ dst, int* __restrict__ cnt) {
  int e = blockIdx.x * blockDim.x + threadIdx.x;
  if (e < N_EDGES) atomicAdd(&cnt[dst[e]], 1);
}

__global__ void chunk_sum_kernel(const int* __restrict__ cnt, int* __restrict__ bsum) {
  __shared__ int s[512];
  int i = blockIdx.x * 512 + threadIdx.x;
  s[threadIdx.x] = (i < N_NODES) ? cnt[i] : 0;
  __syncthreads();
  for (int off = 256; off > 0; off >>= 1) {
    if (threadIdx.x < off) s[threadIdx.x] += s[threadIdx.x + off];
    __syncthreads();
  }
  if (threadIdx.x == 0) bsum[blockIdx.x] = s[0];
}

__global__ void scan_final_kernel(const int* __restrict__ cnt, const int* __restrict__ bsum,
                                  int* __restrict__ row_ptr, float* __restrict__ inv_deg) {
  __shared__ int s[512];
  __shared__ int base_sh;
  int b = blockIdx.x;
  int t = threadIdx.x;
  if (t < 64) {
    int acc = 0;
    for (int i = t; i < b; i += 64) acc += bsum[i];
    #pragma unroll
    for (int m = 1; m <= 32; m <<= 1) acc += __shfl_xor(acc, m);
    if (t == 0) base_sh = acc;
  }
  int i = b * 512 + t;
  int v = (i < N_NODES) ? cnt[i] : 0;
  s[t] = v;
  __syncthreads();
  for (int off = 1; off < 512; off <<= 1) {
    int u = (t >= off) ? s[t - off] : 0;
    __syncthreads();
    s[t] += u;
    __syncthreads();
  }
  if (i < N_NODES) {
    row_ptr[i + 1] = base_sh + s[t];
    if (i == 0) row_ptr[0] = 0;
    inv_deg[i] = 1.0f / fmaxf((float)v, 1.0f);
  }
}

__global__ void fill_csr_kernel(const int* __restrict__ src, const int* __restrict__ dst,
                                const int* __restrict__ row_ptr, int* __restrict__ fill,
                                int* __restrict__ col) {
  int e = blockIdx.x * blockDim.x + threadIdx.x;
  if (e < N_EDGES) {
    int d = dst[e];
    int pos = row_ptr[d] + atomicAdd(&fill[d], 1);
    col[pos] = src[e];
  }
}

// ---------------------------------------------------------------------------
// Aggregation: 1 wave per node, 16-lane groups gather different edges.
// ---------------------------------------------------------------------------
#define ACC8(v)                                          \
  do {                                                   \
    a[0] += bf2f_lo((v)[0]); a[1] += bf2f_hi((v)[0]);    \
    a[2] += bf2f_lo((v)[1]); a[3] += bf2f_hi((v)[1]);    \
    a[4] += bf2f_lo((v)[2]); a[5] += bf2f_hi((v)[2]);    \
    a[6] += bf2f_lo((v)[3]); a[7] += bf2f_hi((v)[3]);    \
  } while (0)

__global__ void agg_mean_bf16(const unsigned short* __restrict__ xb, const int* __restrict__ rp,
                              const int* __restrict__ cl, const float* __restrict__ idg,
                              unsigned short* __restrict__ out) {
  int node = blockIdx.x * 4 + (threadIdx.x >> 6);
  int lane = threadIdx.x & 63;
  int g = lane >> 4, l = lane & 15;
  int beg = rp[node], end = rp[node + 1];
  float a[8] = {0.f, 0.f, 0.f, 0.f, 0.f, 0.f, 0.f, 0.f};
  for (int e0 = beg; e0 < end; e0 += 8) {
    int e1 = e0 + g, e2 = e0 + 4 + g;
    if (e1 < end) {
      u32x4 v = *(const u32x4*)(xb + (size_t)cl[e1] * 128 + l * 8);
      ACC8(v);
    }
    if (e2 < end) {
      u32x4 v = *(const u32x4*)(xb + (size_t)cl[e2] * 128 + l * 8);
      ACC8(v);
    }
  }
  #pragma unroll
  for (int i = 0; i < 8; i++) {
    a[i] += __shfl_xor(a[i], 16);
    a[i] += __shfl_xor(a[i], 32);
  }
  if (g == 0) {
    float s = idg[node];
    u32x4 o;
    #pragma unroll
    for (int i = 0; i < 4; i++)
      o[i] = (unsigned int)f2bf(a[2 * i] * s) | ((unsigned int)f2bf(a[2 * i + 1] * s) << 16);
    *(u32x4*)(out + (size_t)node * 128 + l * 8) = o;
  }
}

// h = relu(l2norm(mean_gather(yl) + bias + yr_row)), F=128, bf16 out
__global__ void agg_nr128(const unsigned short* __restrict__ yl, const unsigned short* __restrict__ yr,
                          const float* __restrict__ bias, const int* __restrict__ rp,
                          const int* __restrict__ cl, const float* __restrict__ idg,
                          unsigned short* __restrict__ outb) {
  int node = blockIdx.x * 4 + (threadIdx.x >> 6);
  int lane = threadIdx.x & 63;
  int g = lane >> 4, l = lane & 15;
  int beg = rp[node], end = rp[node + 1];
  float a[8] = {0.f, 0.f, 0.f, 0.f, 0.f, 0.f, 0.f, 0.f};
  for (int e0 = beg; e0 < end; e0 += 8) {
    int e1 = e0 + g, e2 = e0 + 4 + g;
    if (e1 < end) {
      u32x4 v = *(const u32x4*)(yl + (size_t)cl[e1] * 128 + l * 8);
      ACC8(v);
    }
    if (e2 < end) {
      u32x4 v = *(const u32x4*)(yl + (size_t)cl[e2] * 128 + l * 8);
      ACC8(v);
    }
  }
  #pragma unroll
  for (int i = 0; i < 8; i++) {
    a[i] += __shfl_xor(a[i], 16);
    a[i] += __shfl_xor(a[i], 32);
  }
  float s = idg[node];
  u32x4 r = *(const u32x4*)(yr + (size_t)node * 128 + l * 8);
  float v[8];
  v[0] = a[0] * s + bias[l * 8 + 0] + bf2f_lo(r[0]);
  v[1] = a[1] * s + bias[l * 8 + 1] + bf2f_hi(r[0]);
  v[2] = a[2] * s + bias[l * 8 + 2] + bf2f_lo(r[1]);
  v[3] = a[3] * s + bias[l * 8 + 3] + bf2f_hi(r[1]);
  v[4] = a[4] * s + bias[l * 8 + 4] + bf2f_lo(r[2]);
  v[5] = a[5] * s + bias[l * 8 + 5] + bf2f_hi(r[2]);
  v[6] = a[6] * s + bias[l * 8 + 6] + bf2f_lo(r[3]);
  v[7] = a[7] * s + bias[l * 8 + 7] + bf2f_hi(r[3]);
  float p = 0.f;
  #pragma unroll
  for (int i = 0; i < 8; i++) p += v[i] * v[i];
  #pragma unroll
  for (int msk = 1; msk <= 8; msk <<= 1) p += __shfl_xor(p, msk);
  float sc = 1.0f / fmaxf(sqrtf(p), 1e-12f);
  if (g == 0) {
    u32x4 o;
    #pragma unroll
    for (int i = 0; i < 4; i++) {
      float w0 = fmaxf(v[2 * i] * sc, 0.f);
      float w1 = fmaxf(v[2 * i + 1] * sc, 0.f);
      o[i] = (unsigned int)f2bf(w0) | ((unsigned int)f2bf(w1) << 16);
    }
    *(u32x4*)(outb + (size_t)node * 128 + l * 8) = o;
  }
}

// Layer-3 epilogue + FUSED FC partial:
// h3 = relu(l2norm(mean_gather(yl) + bias + yr_row)), F=64 (kept in regs);
// partial[block*5+c] = sum over block's 4 nodes of dot(h3[node], fcW[c, node*64..])
__global__ void agg_nr64_fc(const unsigned short* __restrict__ yl, const unsigned short* __restrict__ yr,
                            const float* __restrict__ bias, const int* __restrict__ rp,
                            const int* __restrict__ cl, const float* __restrict__ idg,
                            const float* __restrict__ fcW, float* __restrict__ partial) {
  __shared__ float wsum[4][5];
  const size_t L = (size_t)N_NODES * 64;
  int wave = threadIdx.x >> 6;
  int node = blockIdx.x * 4 + wave;
  int lane = threadIdx.x & 63;
  int g = lane >> 3, l = lane & 7;
  int beg = rp[node], end = rp[node + 1];
  float a[8] = {0.f, 0.f, 0.f, 0.f, 0.f, 0.f, 0.f, 0.f};
  for (int e0 = beg; e0 < end; e0 += 16) {
    int e1 = e0 + g, e2 = e0 + 8 + g;
    if (e1 < end) {
      u32x4 v = *(const u32x4*)(yl + (size_t)cl[e1] * 64 + l * 8);
      ACC8(v);
    }
    if (e2 < end) {
      u32x4 v = *(const u32x4*)(yl + (size_t)cl[e2] * 64 + l * 8);
      ACC8(v);
    }
  }
  #pragma unroll
  for (int i = 0; i < 8; i++) {
    a[i] += __shfl_xor(a[i], 8);
    a[i] += __shfl_xor(a[i], 16);
    a[i] += __shfl_xor(a[i], 32);
  }
  float s = idg[node];
  u32x4 r = *(const u32x4*)(yr + (size_t)node * 64 + l * 8);
  float v[8];
  v[0] = a[0] * s + bias[l * 8 + 0] + bf2f_lo(r[0]);
  v[1] = a[1] * s + bias[l * 8 + 1] + bf2f_hi(r[0]);
  v[2] = a[2] * s + bias[l * 8 + 2] + bf2f_lo(r[1]);
  v[3] = a[3] * s + bias[l * 8 + 3] + bf2f_hi(r[1]);
  v[4] = a[4] * s + bias[l * 8 + 4] + bf2f_lo(r[2]);
  v[5] = a[5] * s + bias[l * 8 + 5] + bf2f_hi(r[2]);
  v[6] = a[6] * s + bias[l * 8 + 6] + bf2f_lo(r[3]);
  v[7] = a[7] * s + bias[l * 8 + 7] + bf2f_hi(r[3]);
  float p = 0.f;
  #pragma unroll
  for (int i = 0; i < 8; i++) p += v[i] * v[i];
  #pragma unroll
  for (int msk = 1; msk <= 4; msk <<= 1) p += __shfl_xor(p, msk);
  float sc = 1.0f / fmaxf(sqrtf(p), 1e-12f);
  // h3 row for this node: lanes g==0 (l=0..7) hold cols l*8..l*8+7
  if (g == 0) {
    float h[8];
    #pragma unroll
    for (int i = 0; i < 8; i++) h[i] = fmaxf(v[i] * sc, 0.f);
    const float* fw = fcW + (size_t)node * 64 + l * 8;
    float cls[5];
    #pragma unroll
    for (int c = 0; c < 5; c++) {
      f32x4 w0 = *(const f32x4*)(fw + (size_t)c * L);
      f32x4 w1 = *(const f32x4*)(fw + (size_t)c * L + 4);
      float d = h[0] * w0[0] + h[1] * w0[1] + h[2] * w0[2] + h[3] * w0[3] +
                h[4] * w1[0] + h[5] * w1[1] + h[6] * w1[2] + h[7] * w1[3];
      #pragma unroll
      for (int msk = 1; msk <= 4; msk <<= 1) d += __shfl_xor(d, msk);
      cls[c] = d;
    }
    if (l == 0) {
      #pragma unroll
      for (int c = 0; c < 5; c++) wsum[wave][c] = cls[c];
    }
  }
  __syncthreads();
  if (threadIdx.x < 5) {
    partial[(size_t)blockIdx.x * 5 + threadIdx.x] =
        wsum[0][threadIdx.x] + wsum[1][threadIdx.x] + wsum[2][threadIdx.x] + wsum[3][threadIdx.x];
  }
}

// ---------------------------------------------------------------------------
// Fused layer1+layer2 GEMM, 128-row tile, 512 threads = 8 column-waves.
// (round-8 configuration: best measured, total 205 us)
// ---------------------------------------------------------------------------
__launch_bounds__(512, 4)
__global__ void gemm12_kernel(const unsigned short* __restrict__ A1,  // mean1
                              const unsigned short* __restrict__ A2,  // xb
                              const unsigned short* __restrict__ W1, const float* __restrict__ b1,
                              const unsigned short* __restrict__ W2,
                              unsigned short* __restrict__ y2l, unsigned short* __restrict__ y2r) {
  __shared__ unsigned char As[128 * 512];
  __shared__ float sums[128][9];
  const int tid = threadIdx.x;
  const int wave = tid >> 6, lane = tid & 63;
  const int l15 = lane & 15, kg = lane >> 4;
  const int row0 = blockIdx.x * 128;
  const int wj = wave * 32;

  // ---- stage [mean1|xb] tile: load ALL 8 first, then write ----
  u32x4 sv[8];
  #pragma unroll
  for (int i = 0; i < 8; i++) {
    int boff = i * 8192 + tid * 16;
    int row = boff >> 9;
    int colb = boff & 511;
    int grow = row0 + row; if (grow >= N_NODES) grow = N_NODES - 1;
    if (colb < 256) sv[i] = *(const u32x4*)((const char*)A1 + (size_t)grow * 256 + colb);
    else            sv[i] = *(const u32x4*)((const char*)A2 + (size_t)grow * 256 + colb - 256);
  }
  #pragma unroll
  for (int i = 0; i < 8; i++) {
    int boff = i * 8192 + tid * 16;
    int row = boff >> 9;
    int colb = boff & 511;
    *(u32x4*)(&As[row * 512 + (colb ^ ((row & 7) << 4))]) = sv[i];
  }

  f32x4 acc[2][8];
  #pragma unroll
  for (int jf = 0; jf < 2; jf++)
    #pragma unroll
    for (int rf = 0; rf < 8; rf++) acc[jf][rf] = (f32x4){0.f, 0.f, 0.f, 0.f};

  const unsigned short* Wp1 = W1 + (size_t)(wj + l15) * 256 + kg * 8;
  bf16x8 wc[2], wn[2];
  #pragma unroll
  for (int jf = 0; jf < 2; jf++) wc[jf] = ld8(Wp1 + jf * 4096);

  __syncthreads();

  // ---- layer-1 k-loop ----
  #pragma unroll
  for (int k0 = 0; k0 < 256; k0 += 32) {
    if (k0 < 224) {
      #pragma unroll
      for (int jf = 0; jf < 2; jf++) wn[jf] = ld8(Wp1 + jf * 4096 + k0 + 32);
    }
    int colb = (k0 + kg * 8) * 2;
    #pragma unroll
    for (int h = 0; h < 2; h++) {
      bf16x8 af[4];
      #pragma unroll
      for (int mf = 0; mf < 4; mf++) {
        int row = h * 64 + mf * 16 + l15;
        af[mf] = ld8((const unsigned short*)&As[row * 512 + (colb ^ ((row & 7) << 4))]);
      }
      #pragma unroll
      for (int jf = 0; jf < 2; jf++)
        #pragma unroll
        for (int mf = 0; mf < 4; mf++)
          acc[jf][h * 4 + mf] =
              __builtin_amdgcn_mfma_f32_16x16x32_bf16(wc[jf], af[mf], acc[jf][h * 4 + mf], 0, 0, 0);
    }
    if (k0 < 224) {
      #pragma unroll
      for (int jf = 0; jf < 2; jf++) wc[jf] = wn[jf];
    }
  }

  // ---- epilogue 1: bias + L2-norm + relu (8-wave reduce over 128 rows) ----
  {
    float p[8] = {0.f, 0.f, 0.f, 0.f, 0.f, 0.f, 0.f, 0.f};
    #pragma unroll
    for (int jf = 0; jf < 2; jf++)
      #pragma unroll
      for (int r = 0; r < 4; r++) {
        float bj = b1[wj + jf * 16 + kg * 4 + r];
        #pragma unroll
        for (int rf = 0; rf < 8; rf++) {
          float v = acc[jf][rf][r] + bj;
          acc[jf][rf][r] = v;
          p[rf] += v * v;
        }
      }
    #pragma unroll
    for (int rf = 0; rf < 8; rf++) {
      p[rf] += __shfl_xor(p[rf], 16);
      p[rf] += __shfl_xor(p[rf], 32);
    }
    if (kg == 0) {
      #pragma unroll
      for (int rf = 0; rf < 8; rf++) sums[rf * 16 + l15][wave] = p[rf];
    }
    __syncthreads();
    #pragma unroll
    for (int rf = 0; rf < 8; rf++) {
      int rl = rf * 16 + l15;
      float tot = 0.f;
      #pragma unroll
      for (int w = 0; w < 8; w++) tot += sums[rl][w];
      float sc = 1.0f / fmaxf(sqrtf(tot), 1e-12f);
      #pragma unroll
      for (int jf = 0; jf < 2; jf++)
        #pragma unroll
        for (int r = 0; r < 4; r++) acc[jf][rf][r] = fmaxf(acc[jf][rf][r] * sc, 0.f);
    }
  }

  __syncthreads();   // all As reads of loop 1 done before overwrite

  // ---- write h1 into As (same swizzle), preload W2 ----
  #pragma unroll
  for (int rf = 0; rf < 8; rf++) {
    int row = rf * 16 + l15;
    #pragma unroll
    for (int jf = 0; jf < 2; jf++) {
      ushort4 o;
      o.x = f2bf(acc[jf][rf][0]);
      o.y = f2bf(acc[jf][rf][1]);
      o.z = f2bf(acc[jf][rf][2]);
      o.w = f2bf(acc[jf][rf][3]);
      int colb = (wj + jf * 16 + kg * 4) * 2;
      *(ushort4*)(&As[row * 512 + (colb ^ ((row & 7) << 4))]) = o;
    }
  }
  const unsigned short* Wp2 = W2 + (size_t)(wj + l15) * 256 + kg * 8;
  #pragma unroll
  for (int jf = 0; jf < 2; jf++) wc[jf] = ld8(Wp2 + jf * 4096);
  #pragma unroll
  for (int jf = 0; jf < 2; jf++)
    #pragma unroll
    for (int rf = 0; rf < 8; rf++) acc[jf][rf] = (f32x4){0.f, 0.f, 0.f, 0.f};

  __syncthreads();   // h1 visible to all waves

  // ---- layer-2 k-loop ----
  #pragma unroll
  for (int k0 = 0; k0 < 256; k0 += 32) {
    if (k0 < 224) {
      #pragma unroll
      for (int jf = 0; jf < 2; jf++) wn[jf] = ld8(Wp2 + jf * 4096 + k0 + 32);
    }
    int colb = (k0 + kg * 8) * 2;
    #pragma unroll
    for (int h = 0; h < 2; h++) {
      bf16x8 af[4];
      #pragma unroll
      for (int mf = 0; mf < 4; mf++) {
        int row = h * 64 + mf * 16 + l15;
        af[mf] = ld8((const unsigned short*)&As[row * 512 + (colb ^ ((row & 7) << 4))]);
      }
      #pragma unroll
      for (int jf = 0; jf < 2; jf++)
        #pragma unroll
        for (int mf = 0; mf < 4; mf++)
          acc[jf][h * 4 + mf] =
              __builtin_amdgcn_mfma_f32_16x16x32_bf16(wc[jf], af[mf], acc[jf][h * 4 + mf], 0, 0, 0);
    }
    if (k0 < 224) {
      #pragma unroll
      for (int jf = 0; jf < 2; jf++) wc[jf] = wn[jf];
    }
  }

  // ---- store y2 (col split at 128) ----
  unsigned short* ob = (wj >= 128) ? y2r : y2l;
  int cb = wj & 127;
  #pragma unroll
  for (int rf = 0; rf < 8; rf++) {
    int m = row0 + rf * 16 + l15;
    if (m < N_NODES) {
      #pragma unroll
      for (int jf = 0; jf < 2; jf++) {
        ushort4 o;
        o.x = f2bf(acc[jf][rf][0]);
        o.y = f2bf(acc[jf][rf][1]);
        o.z = f2bf(acc[jf][rf][2]);
        o.w = f2bf(acc[jf][rf][3]);
        *(ushort4*)&ob[(size_t)m * 128 + cb + jf * 16 + kg * 4] = o;
      }
    }
  }
}

// ---------------------------------------------------------------------------
// MFMA GEMM (layer 3), 128-row tile, 512 threads = 8 column-waves (16 cols
// each). acc[8], 1 W-load + 8 MFMA per k-step. (round-8 configuration)
// ---------------------------------------------------------------------------
template<int FI, int FO, bool OSPLIT>
__launch_bounds__(512, 4)
__global__ void mfma_gemm(const unsigned short* __restrict__ A1,
                          const unsigned short* __restrict__ W,
                          unsigned short* __restrict__ outA, unsigned short* __restrict__ outB) {
  constexpr int ROWB = FI * 2;           // 256
  __shared__ unsigned char As[128 * ROWB];
  const int tid = threadIdx.x;
  const int wave = tid >> 6, lane = tid & 63;
  const int l15 = lane & 15, kg = lane >> 4;
  const int row0 = blockIdx.x * 128;
  const int wj = wave * (FO / 8);        // 16 cols per wave

  u32x4 sv[4];
  #pragma unroll
  for (int i = 0; i < 4; i++) {
    int boff = i * 8192 + tid * 16;
    int row = boff / ROWB;
    int colb = boff % ROWB;
    int grow = row0 + row; if (grow >= N_NODES) grow = N_NODES - 1;
    sv[i] = *(const u32x4*)((const char*)A1 + (size_t)grow * ROWB + colb);
  }
  #pragma unroll
  for (int i = 0; i < 4; i++) {
    int boff = i * 8192 + tid * 16;
    int row = boff / ROWB;
    int colb = boff % ROWB;
    *(u32x4*)(&As[row * ROWB + (colb ^ ((row & 7) << 4))]) = sv[i];
  }

  f32x4 acc[8];
  #pragma unroll
  for (int rf = 0; rf < 8; rf++) acc[rf] = (f32x4){0.f, 0.f, 0.f, 0.f};

  const unsigned short* Wp = W + (size_t)(wj + l15) * FI + kg * 8;
  bf16x8 wc = ld8(Wp), wn;

  __syncthreads();

  #pragma unroll
  for (int k0 = 0; k0 < FI; k0 += 32) {
    if (k0 + 32 < FI) wn = ld8(Wp + k0 + 32);
    int colb = (k0 + kg * 8) * 2;
    #pragma unroll
    for (int h = 0; h < 2; h++) {
      bf16x8 af[4];
      #pragma unroll
      for (int mf = 0; mf < 4; mf++) {
        int row = h * 64 + mf * 16 + l15;
        af[mf] = ld8((const unsigned short*)&As[row * ROWB + (colb ^ ((row & 7) << 4))]);
      }
      #pragma unroll
      for (int mf = 0; mf < 4; mf++)
        acc[h * 4 + mf] =
            __builtin_amdgcn_mfma_f32_16x16x32_bf16(wc, af[mf], acc[h * 4 + mf], 0, 0, 0);
    }
    if (k0 + 32 < FI) wc = wn;
  }

  unsigned short* ob = outA;
  int cb = wj;
  constexpr int OSTR = OSPLIT ? FO / 2 : FO;
  if (OSPLIT && wj >= FO / 2) { ob = outB; cb = wj - FO / 2; }
  #pragma unroll
  for (int rf = 0; rf < 8; rf++) {
    int m = row0 + rf * 16 + l15;
    if (m < N_NODES) {
      ushort4 o;
      o.x = f2bf(acc[rf][0]);
      o.y = f2bf(acc[rf][1]);
      o.z = f2bf(acc[rf][2]);
      o.w = f2bf(acc[rf][3]);
      *(ushort4*)&ob[(size_t)m * OSTR + cb + kg * 4] = o;
    }
  }
}

// ---------------------------------------------------------------------------
// FC final: reduce 12500x5 partials, add bias, softmax
// ---------------------------------------------------------------------------
__global__ void fc_final_kernel(const float* __restrict__ partial, const float* __restrict__ fcb,
                                float* __restrict__ out) {
  __shared__ float red[4];
  __shared__ float logits[5];
  int tid = threadIdx.x;
  for (int c = 0; c < 5; c++) {
    float a = 0.f;
    for (int b = tid; b < AGB; b += 256) a += partial[(size_t)b * 5 + c];
    #pragma unroll
    for (int msk = 1; msk <= 32; msk <<= 1) a += __shfl_xor(a, msk);
    if ((tid & 63) == 0) red[tid >> 6] = a;
    __syncthreads();
    if (tid == 0) logits[c] = red[0] + red[1] + red[2] + red[3] + fcb[c];
    __syncthreads();
  }
  if (tid == 0) {
    float mx = logits[0];
    for (int c = 1; c < 5; c++) mx = fmaxf(mx, logits[c]);
    float e[5], s = 0.f;
    for (int c = 0; c < 5; c++) { e[c] = expf(logits[c] - mx); s += e[c]; }
    for (int c = 0; c < 5; c++) out[c] = e[c] / s;
  }
}

// ---------------------------------------------------------------------------
extern "C" void kernel_launch(void* const* d_in, const int* in_sizes, int n_in,
                              void* d_out, int out_size, void* d_ws, size_t ws_size,
                              hipStream_t stream) {
  (void)in_sizes; (void)n_in; (void)out_size; (void)ws_size;
  const float* x   = (const float*)d_in[0];
  const int*   ei  = (const int*)d_in[1];
  const float* W1l = (const float*)d_in[2];
  const float* b1  = (const float*)d_in[3];
  const float* W1r = (const float*)d_in[4];
  const float* W2l = (const float*)d_in[5];
  const float* b2  = (const float*)d_in[6];
  const float* W2r = (const float*)d_in[7];
  const float* W3l = (const float*)d_in[8];
  const float* b3  = (const float*)d_in[9];
  const float* W3r = (const float*)d_in[10];
  const float* fcW = (const float*)d_in[11];
  const float* fcb = (const float*)d_in[12];
  const int* src = ei;
  const int* dst = ei + N_EDGES;

  char* ws = (char*)d_ws;
  size_t off = 0;
  auto alloc = [&](size_t bytes) { void* p = ws + off; off += (bytes + 255) & ~(size_t)255; return p; };
  int*   cntfill = (int*)alloc((size_t)100000 * 4);   // cnt | fill, zeroed in prep
  int*   row_ptr = (int*)alloc((size_t)(N_NODES + 1) * 4);
  int*   bsum    = (int*)alloc(512);
  float* inv_deg = (float*)alloc((size_t)N_NODES * 4);
  int*   col     = (int*)alloc((size_t)N_EDGES * 4);
  unsigned short* w1b = (unsigned short*)alloc((size_t)256 * 256 * 2);
  unsigned short* w2b = (unsigned short*)alloc((size_t)256 * 256 * 2);
  unsigned short* w3b = (unsigned short*)alloc((size_t)128 * 128 * 2);
  float* partial = (float*)alloc((size_t)AGB * 5 * 4);
  unsigned short* B0 = (unsigned short*)alloc((size_t)N_NODES * 128 * 2);  // xb -> y2r
  unsigned short* B1 = (unsigned short*)alloc((size_t)N_NODES * 128 * 2);  // mean1 -> y2l
  unsigned short* B2 = (unsigned short*)alloc((size_t)N_NODES * 256 * 2);  // {y3l, y3r}
  unsigned short* B3 = (unsigned short*)alloc((size_t)N_NODES * 128 * 2);  // h2
  float* out5 = (float*)d_out;

  int*   cnt  = cntfill;
  int*   fill = cntfill + N_NODES;
  unsigned short* xb    = B0;
  unsigned short* mean1 = B1;
  unsigned short* y2l   = B1;   // block-local overwrite of mean1 (same rows only)
  unsigned short* y2r   = B0;   // block-local overwrite of xb (same rows only)
  unsigned short* h2    = B3;
  unsigned short* y3l   = B2;
  unsigned short* y3r   = B2 + (size_t)N_NODES * 64;

  const int NCH = (N_NODES + 511) / 512;  // 98

  // ---- prep: f2b + weight packs + zero cnt/fill (1 kernel) ----
  prep_kernel<<<(1772456 + 255) / 256, 256, 0, stream>>>(
      x, xb, W1l, W1r, w1b, W2l, W2r, w2b, W3l, W3r, w3b, cntfill);

  // ---- CSR build (4 kernels, no serial stage) ----
  hist_kernel<<<(N_EDGES + 255) / 256, 256, 0, stream>>>(dst, cnt);
  chunk_sum_kernel<<<NCH, 512, 0, stream>>>(cnt, bsum);
  scan_final_kernel<<<NCH, 512, 0, stream>>>(cnt, bsum, row_ptr, inv_deg);
  fill_csr_kernel<<<(N_EDGES + 255) / 256, 256, 0, stream>>>(src, dst, row_ptr, fill, col);

  const int GB12 = (N_NODES + 127) / 128;   // 391

  // ---- Layer 1+2 ----
  agg_mean_bf16<<<AGB, 256, 0, stream>>>(xb, row_ptr, col, inv_deg, mean1);
  gemm12_kernel<<<GB12, 512, 0, stream>>>(mean1, xb, w1b, b1, w2b, y2l, y2r);
  agg_nr128<<<AGB, 256, 0, stream>>>(y2l, y2r, b2, row_ptr, col, inv_deg, h2);

  // ---- Layer 3 (+ fused FC partial) ----
  mfma_gemm<128, 128, true><<<GB12, 512, 0, stream>>>(h2, w3b, y3l, y3r);
  agg_nr64_fc<<<AGB, 256, 0, stream>>>(y3l, y3r, b3, row_ptr, col, inv_deg, fcW, partial);

  // ---- FC final + softmax ----
  fc_final_kernel<<<1, 256, 0, stream>>>(partial, fcb, out5);
}

// Round 12
// 204.988 us; speedup vs baseline: 1.1306x; 1.1306x over previous
//
#include <hip/hip_runtime.h>
#include <hip/hip_bf16.h>
#include <math.h>

#define N_NODES 50000
#define N_EDGES 500000
#define FC_BLOCKS 1024

typedef __bf16 bf16x8 __attribute__((ext_vector_type(8)));
typedef float f32x4 __attribute__((ext_vector_type(4)));
typedef unsigned int u32x4 __attribute__((ext_vector_type(4)));

static __device__ __forceinline__ float bf2f_lo(unsigned int v) {
  return __uint_as_float(v << 16);
}
static __device__ __forceinline__ float bf2f_hi(unsigned int v) {
  return __uint_as_float(v & 0xffff0000u);
}
static __device__ __forceinline__ unsigned short f2bf(float f) {
  unsigned int u = __float_as_uint(f);
  return (unsigned short)((u + 0x7fffu + ((u >> 16) & 1u)) >> 16);
}
static __device__ __forceinline__ bf16x8 ld8(const unsigned short* p) {
  u32x4 u = *(const u32x4*)p;
  return __builtin_bit_cast(bf16x8, u);
}

// ---------------------------------------------------------------------------
// Prep: x->bf16, pack W1/W2/W3 to [FO][FI] bf16, zero cnt+fill (contiguous)
// ---------------------------------------------------------------------------
__global__ void prep_kernel(const float* __restrict__ x, unsigned short* __restrict__ xb,
                            const float* __restrict__ W1l, const float* __restrict__ W1r,
                            unsigned short* __restrict__ w1b,
                            const float* __restrict__ W2l, const float* __restrict__ W2r,
                            unsigned short* __restrict__ w2b,
                            const float* __restrict__ W3l, const float* __restrict__ W3r,
                            unsigned short* __restrict__ w3b,
                            int* __restrict__ cntfill) {
  int idx = blockIdx.x * 256 + threadIdx.x;
  if (idx < 1600000) {
    float4 v = ((const float4*)x)[idx];
    ushort4 o;
    o.x = f2bf(v.x); o.y = f2bf(v.y); o.z = f2bf(v.z); o.w = f2bf(v.w);
    ((ushort4*)xb)[idx] = o;
  } else if (idx < 1665536) {
    int i = idx - 1600000;
    int j = i >> 8, k = i & 255;                       // FI=256, kcat FIh=128
    float v = (k < 128) ? W1l[j * 128 + k] : W1r[j * 128 + (k - 128)];
    w1b[i] = f2bf(v);
  } else if (idx < 1731072) {
    int i = idx - 1665536;
    int j = i >> 8, k = i & 255;                       // FI=256, jcat FOh=128
    float v = (j < 128) ? W2l[j * 256 + k] : W2r[(j - 128) * 256 + k];
    w2b[i] = f2bf(v);
  } else if (idx < 1747456) {
    int i = idx - 1731072;
    int j = i >> 7, k = i & 127;                       // FI=128, jcat FOh=64
    float v = (j < 64) ? W3l[j * 128 + k] : W3r[(j - 64) * 128 + k];
    w3b[i] = f2bf(v);
  } else if (idx < 1772456) {
    int i = idx - 1747456;
    ((int4*)cntfill)[i] = make_int4(0, 0, 0, 0);
  }
}

// ---------------------------------------------------------------------------
// CSR build: hist -> chunk sums -> scan_final (inline cross-block offset) -> fill
// ---------------------------------------------------------------------------
__global__ void hist_kernel(const int* __restrict__ dst, int* __restrict__ cnt) {
  int e = blockIdx.x * blockDim.x + threadIdx.x;
  if (e < N_EDGES) atomicAdd(&cnt[dst[e]], 1);
}

__global__ void chunk_sum_kernel(const int* __restrict__ cnt, int* __restrict__ bsum) {
  __shared__ int s[512];
  int i = blockIdx.x * 512 + threadIdx.x;
  s[threadIdx.x] = (i < N_NODES) ? cnt[i] : 0;
  __syncthreads();
  for (int off = 256; off > 0; off >>= 1) {
    if (threadIdx.x < off) s[threadIdx.x] += s[threadIdx.x + off];
    __syncthreads();
  }
  if (threadIdx.x == 0) bsum[blockIdx.x] = s[0];
}

__global__ void scan_final_kernel(const int* __restrict__ cnt, const int* __restrict__ bsum,
                                  int* __restrict__ row_ptr, float* __restrict__ inv_deg) {
  __shared__ int s[512];
  __shared__ int base_sh;
  int b = blockIdx.x;
  int t = threadIdx.x;
  if (t < 64) {
    int acc = 0;
    for (int i = t; i < b; i += 64) acc += bsum[i];
    #pragma unroll
    for (int m = 1; m <= 32; m <<= 1) acc += __shfl_xor(acc, m);
    if (t == 0) base_sh = acc;
  }
  int i = b * 512 + t;
  int v = (i < N_NODES) ? cnt[i] : 0;
  s[t] = v;
  __syncthreads();
  for (int off = 1; off < 512; off <<= 1) {
    int u = (t >= off) ? s[t - off] : 0;
    __syncthreads();
    s[t] += u;
    __syncthreads();
  }
  if (i < N_NODES) {
    row_ptr[i + 1] = base_sh + s[t];
    if (i == 0) row_ptr[0] = 0;
    inv_deg[i] = 1.0f / fmaxf((float)v, 1.0f);
  }
}

__global__ void fill_csr_kernel(const int* __restrict__ src, const int* __restrict__ dst,
                                const int* __restrict__ row_ptr, int* __restrict__ fill,
                                int* __restrict__ col) {
  int e = blockIdx.x * blockDim.x + threadIdx.x;
  if (e < N_EDGES) {
    int d = dst[e];
    int pos = row_ptr[d] + atomicAdd(&fill[d], 1);
    col[pos] = src[e];
  }
}

// ---------------------------------------------------------------------------
// Aggregation: 1 wave per node, 16-lane groups gather different edges.
// 4 edges in flight per group (16 per wave): mean degree ~10 means a typical
// node issues ALL gathers in a single batch.
// ---------------------------------------------------------------------------
#define ACC8(v)                                          \
  do {                                                   \
    a[0] += bf2f_lo((v)[0]); a[1] += bf2f_hi((v)[0]);    \
    a[2] += bf2f_lo((v)[1]); a[3] += bf2f_hi((v)[1]);    \
    a[4] += bf2f_lo((v)[2]); a[5] += bf2f_hi((v)[2]);    \
    a[6] += bf2f_lo((v)[3]); a[7] += bf2f_hi((v)[3]);    \
  } while (0)

__global__ void agg_mean_bf16(const unsigned short* __restrict__ xb, const int* __restrict__ rp,
                              const int* __restrict__ cl, const float* __restrict__ idg,
                              unsigned short* __restrict__ out) {
  int node = blockIdx.x * 4 + (threadIdx.x >> 6);
  int lane = threadIdx.x & 63;
  int g = lane >> 4, l = lane & 15;
  int beg = rp[node], end = rp[node + 1];
  float a[8] = {0.f, 0.f, 0.f, 0.f, 0.f, 0.f, 0.f, 0.f};
  for (int e0 = beg; e0 < end; e0 += 16) {
    #pragma unroll
    for (int u = 0; u < 4; u++) {
      int e = e0 + u * 4 + g;
      if (e < end) {
        u32x4 v = *(const u32x4*)(xb + (size_t)cl[e] * 128 + l * 8);
        ACC8(v);
      }
    }
  }
  #pragma unroll
  for (int i = 0; i < 8; i++) {
    a[i] += __shfl_xor(a[i], 16);
    a[i] += __shfl_xor(a[i], 32);
  }
  if (g == 0) {
    float s = idg[node];
    u32x4 o;
    #pragma unroll
    for (int i = 0; i < 4; i++)
      o[i] = (unsigned int)f2bf(a[2 * i] * s) | ((unsigned int)f2bf(a[2 * i + 1] * s) << 16);
    *(u32x4*)(out + (size_t)node * 128 + l * 8) = o;
  }
}

// h = relu(l2norm(mean_gather(yl) + bias + yr_row)), F=128, bf16 out
__global__ void agg_nr128(const unsigned short* __restrict__ yl, const unsigned short* __restrict__ yr,
                          const float* __restrict__ bias, const int* __restrict__ rp,
                          const int* __restrict__ cl, const float* __restrict__ idg,
                          unsigned short* __restrict__ outb) {
  int node = blockIdx.x * 4 + (threadIdx.x >> 6);
  int lane = threadIdx.x & 63;
  int g = lane >> 4, l = lane & 15;
  int beg = rp[node], end = rp[node + 1];
  float a[8] = {0.f, 0.f, 0.f, 0.f, 0.f, 0.f, 0.f, 0.f};
  for (int e0 = beg; e0 < end; e0 += 16) {
    #pragma unroll
    for (int u = 0; u < 4; u++) {
      int e = e0 + u * 4 + g;
      if (e < end) {
        u32x4 v = *(const u32x4*)(yl + (size_t)cl[e] * 128 + l * 8);
        ACC8(v);
      }
    }
  }
  #pragma unroll
  for (int i = 0; i < 8; i++) {
    a[i] += __shfl_xor(a[i], 16);
    a[i] += __shfl_xor(a[i], 32);
  }
  float s = idg[node];
  u32x4 r = *(const u32x4*)(yr + (size_t)node * 128 + l * 8);
  float v[8];
  v[0] = a[0] * s + bias[l * 8 + 0] + bf2f_lo(r[0]);
  v[1] = a[1] * s + bias[l * 8 + 1] + bf2f_hi(r[0]);
  v[2] = a[2] * s + bias[l * 8 + 2] + bf2f_lo(r[1]);
  v[3] = a[3] * s + bias[l * 8 + 3] + bf2f_hi(r[1]);
  v[4] = a[4] * s + bias[l * 8 + 4] + bf2f_lo(r[2]);
  v[5] = a[5] * s + bias[l * 8 + 5] + bf2f_hi(r[2]);
  v[6] = a[6] * s + bias[l * 8 + 6] + bf2f_lo(r[3]);
  v[7] = a[7] * s + bias[l * 8 + 7] + bf2f_hi(r[3]);
  float p = 0.f;
  #pragma unroll
  for (int i = 0; i < 8; i++) p += v[i] * v[i];
  #pragma unroll
  for (int msk = 1; msk <= 8; msk <<= 1) p += __shfl_xor(p, msk);
  float sc = 1.0f / fmaxf(sqrtf(p), 1e-12f);
  if (g == 0) {
    u32x4 o;
    #pragma unroll
    for (int i = 0; i < 4; i++) {
      float w0 = fmaxf(v[2 * i] * sc, 0.f);
      float w1 = fmaxf(v[2 * i + 1] * sc, 0.f);
      o[i] = (unsigned int)f2bf(w0) | ((unsigned int)f2bf(w1) << 16);
    }
    *(u32x4*)(outb + (size_t)node * 128 + l * 8) = o;
  }
}

// h = relu(l2norm(mean_gather(yl) + bias + yr_row)), F=64, fp32 out
__global__ void agg_nr64(const unsigned short* __restrict__ yl, const unsigned short* __restrict__ yr,
                         const float* __restrict__ bias, const int* __restrict__ rp,
                         const int* __restrict__ cl, const float* __restrict__ idg,
                         float* __restrict__ outf) {
  int node = blockIdx.x * 4 + (threadIdx.x >> 6);
  int lane = threadIdx.x & 63;
  int g = lane >> 3, l = lane & 7;
  int beg = rp[node], end = rp[node + 1];
  float a[8] = {0.f, 0.f, 0.f, 0.f, 0.f, 0.f, 0.f, 0.f};
  for (int e0 = beg; e0 < end; e0 += 16) {
    int e1 = e0 + g, e2 = e0 + 8 + g;
    if (e1 < end) {
      u32x4 v = *(const u32x4*)(yl + (size_t)cl[e1] * 64 + l * 8);
      ACC8(v);
    }
    if (e2 < end) {
      u32x4 v = *(const u32x4*)(yl + (size_t)cl[e2] * 64 + l * 8);
      ACC8(v);
    }
  }
  #pragma unroll
  for (int i = 0; i < 8; i++) {
    a[i] += __shfl_xor(a[i], 8);
    a[i] += __shfl_xor(a[i], 16);
    a[i] += __shfl_xor(a[i], 32);
  }
  float s = idg[node];
  u32x4 r = *(const u32x4*)(yr + (size_t)node * 64 + l * 8);
  float v[8];
  v[0] = a[0] * s + bias[l * 8 + 0] + bf2f_lo(r[0]);
  v[1] = a[1] * s + bias[l * 8 + 1] + bf2f_hi(r[0]);
  v[2] = a[2] * s + bias[l * 8 + 2] + bf2f_lo(r[1]);
  v[3] = a[3] * s + bias[l * 8 + 3] + bf2f_hi(r[1]);
  v[4] = a[4] * s + bias[l * 8 + 4] + bf2f_lo(r[2]);
  v[5] = a[5] * s + bias[l * 8 + 5] + bf2f_hi(r[2]);
  v[6] = a[6] * s + bias[l * 8 + 6] + bf2f_lo(r[3]);
  v[7] = a[7] * s + bias[l * 8 + 7] + bf2f_hi(r[3]);
  float p = 0.f;
  #pragma unroll
  for (int i = 0; i < 8; i++) p += v[i] * v[i];
  #pragma unroll
  for (int msk = 1; msk <= 4; msk <<= 1) p += __shfl_xor(p, msk);
  float sc = 1.0f / fmaxf(sqrtf(p), 1e-12f);
  if (g == 0) {
    f32x4 o0, o1;
    #pragma unroll
    for (int i = 0; i < 4; i++) o0[i] = fmaxf(v[i] * sc, 0.f);
    #pragma unroll
    for (int i = 0; i < 4; i++) o1[i] = fmaxf(v[4 + i] * sc, 0.f);
    *(f32x4*)(outf + (size_t)node * 64 + l * 8) = o0;
    *(f32x4*)(outf + (size_t)node * 64 + l * 8 + 4) = o1;
  }
}

// ---------------------------------------------------------------------------
// Fused layer1+layer2 GEMM, 128-row tile, 512 threads = 8 column-waves.
// (round-9 configuration: best measured, total 205 us)
// ---------------------------------------------------------------------------
__launch_bounds__(512, 4)
__global__ void gemm12_kernel(const unsigned short* __restrict__ A1,  // mean1
                              const unsigned short* __restrict__ A2,  // xb
                              const unsigned short* __restrict__ W1, const float* __restrict__ b1,
                              const unsigned short* __restrict__ W2,
                              unsigned short* __restrict__ y2l, unsigned short* __restrict__ y2r) {
  __shared__ unsigned char As[128 * 512];
  __shared__ float sums[128][9];
  const int tid = threadIdx.x;
  const int wave = tid >> 6, lane = tid & 63;
  const int l15 = lane & 15, kg = lane >> 4;
  const int row0 = blockIdx.x * 128;
  const int wj = wave * 32;

  // ---- stage [mean1|xb] tile: load ALL 8 first, then write ----
  u32x4 sv[8];
  #pragma unroll
  for (int i = 0; i < 8; i++) {
    int boff = i * 8192 + tid * 16;
    int row = boff >> 9;
    int colb = boff & 511;
    int grow = row0 + row; if (grow >= N_NODES) grow = N_NODES - 1;
    if (colb < 256) sv[i] = *(const u32x4*)((const char*)A1 + (size_t)grow * 256 + colb);
    else            sv[i] = *(const u32x4*)((const char*)A2 + (size_t)grow * 256 + colb - 256);
  }
  #pragma unroll
  for (int i = 0; i < 8; i++) {
    int boff = i * 8192 + tid * 16;
    int row = boff >> 9;
    int colb = boff & 511;
    *(u32x4*)(&As[row * 512 + (colb ^ ((row & 7) << 4))]) = sv[i];
  }

  f32x4 acc[2][8];
  #pragma unroll
  for (int jf = 0; jf < 2; jf++)
    #pragma unroll
    for (int rf = 0; rf < 8; rf++) acc[jf][rf] = (f32x4){0.f, 0.f, 0.f, 0.f};

  const unsigned short* Wp1 = W1 + (size_t)(wj + l15) * 256 + kg * 8;
  bf16x8 wc[2], wn[2];
  #pragma unroll
  for (int jf = 0; jf < 2; jf++) wc[jf] = ld8(Wp1 + jf * 4096);

  __syncthreads();

  // ---- layer-1 k-loop ----
  #pragma unroll
  for (int k0 = 0; k0 < 256; k0 += 32) {
    if (k0 < 224) {
      #pragma unroll
      for (int jf = 0; jf < 2; jf++) wn[jf] = ld8(Wp1 + jf * 4096 + k0 + 32);
    }
    int colb = (k0 + kg * 8) * 2;
    #pragma unroll
    for (int h = 0; h < 2; h++) {
      bf16x8 af[4];
      #pragma unroll
      for (int mf = 0; mf < 4; mf++) {
        int row = h * 64 + mf * 16 + l15;
        af[mf] = ld8((const unsigned short*)&As[row * 512 + (colb ^ ((row & 7) << 4))]);
      }
      #pragma unroll
      for (int jf = 0; jf < 2; jf++)
        #pragma unroll
        for (int mf = 0; mf < 4; mf++)
          acc[jf][h * 4 + mf] =
              __builtin_amdgcn_mfma_f32_16x16x32_bf16(wc[jf], af[mf], acc[jf][h * 4 + mf], 0, 0, 0);
    }
    if (k0 < 224) {
      #pragma unroll
      for (int jf = 0; jf < 2; jf++) wc[jf] = wn[jf];
    }
  }

  // ---- epilogue 1: bias + L2-norm + relu (8-wave reduce over 128 rows) ----
  {
    float p[8] = {0.f, 0.f, 0.f, 0.f, 0.f, 0.f, 0.f, 0.f};
    #pragma unroll
    for (int jf = 0; jf < 2; jf++)
      #pragma unroll
      for (int r = 0; r < 4; r++) {
        float bj = b1[wj + jf * 16 + kg * 4 + r];
        #pragma unroll
        for (int rf = 0; rf < 8; rf++) {
          float v = acc[jf][rf][r] + bj;
          acc[jf][rf][r] = v;
          p[rf] += v * v;
        }
      }
    #pragma unroll
    for (int rf = 0; rf < 8; rf++) {
      p[rf] += __shfl_xor(p[rf], 16);
      p[rf] += __shfl_xor(p[rf], 32);
    }
    if (kg == 0) {
      #pragma unroll
      for (int rf = 0; rf < 8; rf++) sums[rf * 16 + l15][wave] = p[rf];
    }
    __syncthreads();
    #pragma unroll
    for (int rf = 0; rf < 8; rf++) {
      int rl = rf * 16 + l15;
      float tot = 0.f;
      #pragma unroll
      for (int w = 0; w < 8; w++) tot += sums[rl][w];
      float sc = 1.0f / fmaxf(sqrtf(tot), 1e-12f);
      #pragma unroll
      for (int jf = 0; jf < 2; jf++)
        #pragma unroll
        for (int r = 0; r < 4; r++) acc[jf][rf][r] = fmaxf(acc[jf][rf][r] * sc, 0.f);
    }
  }

  __syncthreads();   // all As reads of loop 1 done before overwrite

  // ---- write h1 into As (same swizzle), preload W2 ----
  #pragma unroll
  for (int rf = 0; rf < 8; rf++) {
    int row = rf * 16 + l15;
    #pragma unroll
    for (int jf = 0; jf < 2; jf++) {
      ushort4 o;
      o.x = f2bf(acc[jf][rf][0]);
      o.y = f2bf(acc[jf][rf][1]);
      o.z = f2bf(acc[jf][rf][2]);
      o.w = f2bf(acc[jf][rf][3]);
      int colb = (wj + jf * 16 + kg * 4) * 2;
      *(ushort4*)(&As[row * 512 + (colb ^ ((row & 7) << 4))]) = o;
    }
  }
  const unsigned short* Wp2 = W2 + (size_t)(wj + l15) * 256 + kg * 8;
  #pragma unroll
  for (int jf = 0; jf < 2; jf++) wc[jf] = ld8(Wp2 + jf * 4096);
  #pragma unroll
  for (int jf = 0; jf < 2; jf++)
    #pragma unroll
    for (int rf = 0; rf < 8; rf++) acc[jf][rf] = (f32x4){0.f, 0.f, 0.f, 0.f};

  __syncthreads();   // h1 visible to all waves

  // ---- layer-2 k-loop ----
  #pragma unroll
  for (int k0 = 0; k0 < 256; k0 += 32) {
    if (k0 < 224) {
      #pragma unroll
      for (int jf = 0; jf < 2; jf++) wn[jf] = ld8(Wp2 + jf * 4096 + k0 + 32);
    }
    int colb = (k0 + kg * 8) * 2;
    #pragma unroll
    for (int h = 0; h < 2; h++) {
      bf16x8 af[4];
      #pragma unroll
      for (int mf = 0; mf < 4; mf++) {
        int row = h * 64 + mf * 16 + l15;
        af[mf] = ld8((const unsigned short*)&As[row * 512 + (colb ^ ((row & 7) << 4))]);
      }
      #pragma unroll
      for (int jf = 0; jf < 2; jf++)
        #pragma unroll
        for (int mf = 0; mf < 4; mf++)
          acc[jf][h * 4 + mf] =
              __builtin_amdgcn_mfma_f32_16x16x32_bf16(wc[jf], af[mf], acc[jf][h * 4 + mf], 0, 0, 0);
    }
    if (k0 < 224) {
      #pragma unroll
      for (int jf = 0; jf < 2; jf++) wc[jf] = wn[jf];
    }
  }

  // ---- store y2 (col split at 128) ----
  unsigned short* ob = (wj >= 128) ? y2r : y2l;
  int cb = wj & 127;
  #pragma unroll
  for (int rf = 0; rf < 8; rf++) {
    int m = row0 + rf * 16 + l15;
    if (m < N_NODES) {
      #pragma unroll
      for (int jf = 0; jf < 2; jf++) {
        ushort4 o;
        o.x = f2bf(acc[jf][rf][0]);
        o.y = f2bf(acc[jf][rf][1]);
        o.z = f2bf(acc[jf][rf][2]);
        o.w = f2bf(acc[jf][rf][3]);
        *(ushort4*)&ob[(size_t)m * 128 + cb + jf * 16 + kg * 4] = o;
      }
    }
  }
}

// ---------------------------------------------------------------------------
// MFMA GEMM (layer 3), 128-row tile, 512 threads = 8 column-waves (16 cols
// each). acc[8], 1 W-load + 8 MFMA per k-step. (round-9 configuration)
// ---------------------------------------------------------------------------
template<int FI, int FO, bool OSPLIT>
__launch_bounds__(512, 4)
__global__ void mfma_gemm(const unsigned short* __restrict__ A1,
                          const unsigned short* __restrict__ W,
                          unsigned short* __restrict__ outA, unsigned short* __restrict__ outB) {
  constexpr int ROWB = FI * 2;           // 256
  __shared__ unsigned char As[128 * ROWB];
  const int tid = threadIdx.x;
  const int wave = tid >> 6, lane = tid & 63;
  const int l15 = lane & 15, kg = lane >> 4;
  const int row0 = blockIdx.x * 128;
  const int wj = wave * (FO / 8);        // 16 cols per wave

  u32x4 sv[4];
  #pragma unroll
  for (int i = 0; i < 4; i++) {
    int boff = i * 8192 + tid * 16;
    int row = boff / ROWB;
    int colb = boff % ROWB;
    int grow = row0 + row; if (grow >= N_NODES) grow = N_NODES - 1;
    sv[i] = *(const u32x4*)((const char*)A1 + (size_t)grow * ROWB + colb);
  }
  #pragma unroll
  for (int i = 0; i < 4; i++) {
    int boff = i * 8192 + tid * 16;
    int row = boff / ROWB;
    int colb = boff % ROWB;
    *(u32x4*)(&As[row * ROWB + (colb ^ ((row & 7) << 4))]) = sv[i];
  }

  f32x4 acc[8];
  #pragma unroll
  for (int rf = 0; rf < 8; rf++) acc[rf] = (f32x4){0.f, 0.f, 0.f, 0.f};

  const unsigned short* Wp = W + (size_t)(wj + l15) * FI + kg * 8;
  bf16x8 wc = ld8(Wp), wn;

  __syncthreads();

  #pragma unroll
  for (int k0 = 0; k0 < FI; k0 += 32) {
    if (k0 + 32 < FI) wn = ld8(Wp + k0 + 32);
    int colb = (k0 + kg * 8) * 2;
    #pragma unroll
    for (int h = 0; h < 2; h++) {
      bf16x8 af[4];
      #pragma unroll
      for (int mf = 0; mf < 4; mf++) {
        int row = h * 64 + mf * 16 + l15;
        af[mf] = ld8((const unsigned short*)&As[row * ROWB + (colb ^ ((row & 7) << 4))]);
      }
      #pragma unroll
      for (int mf = 0; mf < 4; mf++)
        acc[h * 4 + mf] =
            __builtin_amdgcn_mfma_f32_16x16x32_bf16(wc, af[mf], acc[h * 4 + mf], 0, 0, 0);
    }
    if (k0 + 32 < FI) wc = wn;
  }

  unsigned short* ob = outA;
  int cb = wj;
  constexpr int OSTR = OSPLIT ? FO / 2 : FO;
  if (OSPLIT && wj >= FO / 2) { ob = outB; cb = wj - FO / 2; }
  #pragma unroll
  for (int rf = 0; rf < 8; rf++) {
    int m = row0 + rf * 16 + l15;
    if (m < N_NODES) {
      ushort4 o;
      o.x = f2bf(acc[rf][0]);
      o.y = f2bf(acc[rf][1]);
      o.z = f2bf(acc[rf][2]);
      o.w = f2bf(acc[rf][3]);
      *(ushort4*)&ob[(size_t)m * OSTR + cb + kg * 4] = o;
    }
  }
}

// ---------------------------------------------------------------------------
// FC: logits = fcW @ h3.flat + fcb; softmax
// ---------------------------------------------------------------------------
__global__ void fc_partial_kernel(const float* __restrict__ fcW, const float* __restrict__ h3,
                                  float* __restrict__ partial) {
  const size_t L = (size_t)N_NODES * 64;
  float acc[5] = {0.f, 0.f, 0.f, 0.f, 0.f};
  for (size_t i = (size_t)blockIdx.x * 256 + threadIdx.x; i < L; i += (size_t)gridDim.x * 256) {
    float h = h3[i];
    #pragma unroll
    for (int c = 0; c < 5; c++) acc[c] += h * fcW[(size_t)c * L + i];
  }
  __shared__ float red[4][5];
  #pragma unroll
  for (int msk = 1; msk <= 32; msk <<= 1)
    #pragma unroll
    for (int c = 0; c < 5; c++) acc[c] += __shfl_xor(acc[c], msk);
  int lane = threadIdx.x & 63, wave = threadIdx.x >> 6;
  if (lane == 0)
    #pragma unroll
    for (int c = 0; c < 5; c++) red[wave][c] = acc[c];
  __syncthreads();
  if (threadIdx.x < 5) {
    float s = red[0][threadIdx.x] + red[1][threadIdx.x] + red[2][threadIdx.x] + red[3][threadIdx.x];
    partial[blockIdx.x * 5 + threadIdx.x] = s;
  }
}

__global__ void fc_final_kernel(const float* __restrict__ partial, const float* __restrict__ fcb,
                                float* __restrict__ out) {
  __shared__ float red[4];
  __shared__ float logits[5];
  int tid = threadIdx.x;
  for (int c = 0; c < 5; c++) {
    float a = 0.f;
    for (int b = tid; b < FC_BLOCKS; b += 256) a += partial[b * 5 + c];
    #pragma unroll
    for (int msk = 1; msk <= 32; msk <<= 1) a += __shfl_xor(a, msk);
    if ((tid & 63) == 0) red[tid >> 6] = a;
    __syncthreads();
    if (tid == 0) logits[c] = red[0] + red[1] + red[2] + red[3] + fcb[c];
    __syncthreads();
  }
  if (tid == 0) {
    float mx = logits[0];
    for (int c = 1; c < 5; c++) mx = fmaxf(mx, logits[c]);
    float e[5], s = 0.f;
    for (int c = 0; c < 5; c++) { e[c] = expf(logits[c] - mx); s += e[c]; }
    for (int c = 0; c < 5; c++) out[c] = e[c] / s;
  }
}

// ---------------------------------------------------------------------------
extern "C" void kernel_launch(void* const* d_in, const int* in_sizes, int n_in,
                              void* d_out, int out_size, void* d_ws, size_t ws_size,
                              hipStream_t stream) {
  (void)in_sizes; (void)n_in; (void)out_size; (void)ws_size;
  const float* x   = (const float*)d_in[0];
  const int*   ei  = (const int*)d_in[1];
  const float* W1l = (const float*)d_in[2];
  const float* b1  = (const float*)d_in[3];
  const float* W1r = (const float*)d_in[4];
  const float* W2l = (const float*)d_in[5];
  const float* b2  = (const float*)d_in[6];
  const float* W2r = (const float*)d_in[7];
  const float* W3l = (const float*)d_in[8];
  const float* b3  = (const float*)d_in[9];
  const float* W3r = (const float*)d_in[10];
  const float* fcW = (const float*)d_in[11];
  const float* fcb = (const float*)d_in[12];
  const int* src = ei;
  const int* dst = ei + N_EDGES;

  char* ws = (char*)d_ws;
  size_t off = 0;
  auto alloc = [&](size_t bytes) { void* p = ws + off; off += (bytes + 255) & ~(size_t)255; return p; };
  int*   cntfill = (int*)alloc((size_t)100000 * 4);   // cnt | fill, zeroed in prep
  int*   row_ptr = (int*)alloc((size_t)(N_NODES + 1) * 4);
  int*   bsum    = (int*)alloc(512);
  float* inv_deg = (float*)alloc((size_t)N_NODES * 4);
  int*   col     = (int*)alloc((size_t)N_EDGES * 4);
  unsigned short* w1b = (unsigned short*)alloc((size_t)256 * 256 * 2);
  unsigned short* w2b = (unsigned short*)alloc((size_t)256 * 256 * 2);
  unsigned short* w3b = (unsigned short*)alloc((size_t)128 * 128 * 2);
  float* partial = (float*)alloc((size_t)FC_BLOCKS * 5 * 4);
  unsigned short* B0 = (unsigned short*)alloc((size_t)N_NODES * 128 * 2);  // xb -> y2r
  unsigned short* B1 = (unsigned short*)alloc((size_t)N_NODES * 128 * 2);  // mean1 -> y2l
  unsigned short* B2 = (unsigned short*)alloc((size_t)N_NODES * 256 * 2);  // {y3l, y3r}
  unsigned short* B3 = (unsigned short*)alloc((size_t)N_NODES * 128 * 2);  // h2
  float* B4 = (float*)alloc((size_t)N_NODES * 64 * 4);                      // h3 (fp32 for FC)
  float* out5 = (float*)d_out;

  int*   cnt  = cntfill;
  int*   fill = cntfill + N_NODES;
  unsigned short* xb    = B0;
  unsigned short* mean1 = B1;
  unsigned short* y2l   = B1;   // block-local overwrite of mean1 (same rows only)
  unsigned short* y2r   = B0;   // block-local overwrite of xb (same rows only)
  unsigned short* h2    = B3;
  unsigned short* y3l   = B2;
  unsigned short* y3r   = B2 + (size_t)N_NODES * 64;
  float*          h3f   = B4;

  const int NCH = (N_NODES + 511) / 512;  // 98

  // ---- prep: f2b + weight packs + zero cnt/fill (1 kernel) ----
  prep_kernel<<<(1772456 + 255) / 256, 256, 0, stream>>>(
      x, xb, W1l, W1r, w1b, W2l, W2r, w2b, W3l, W3r, w3b, cntfill);

  // ---- CSR build (4 kernels, no serial stage) ----
  hist_kernel<<<(N_EDGES + 255) / 256, 256, 0, stream>>>(dst, cnt);
  chunk_sum_kernel<<<NCH, 512, 0, stream>>>(cnt, bsum);
  scan_final_kernel<<<NCH, 512, 0, stream>>>(cnt, bsum, row_ptr, inv_deg);
  fill_csr_kernel<<<(N_EDGES + 255) / 256, 256, 0, stream>>>(src, dst, row_ptr, fill, col);

  const int AGB = N_NODES / 4;              // 12500
  const int GB12 = (N_NODES + 127) / 128;   // 391

  // ---- Layer 1+2 ----
  agg_mean_bf16<<<AGB, 256, 0, stream>>>(xb, row_ptr, col, inv_deg, mean1);
  gemm12_kernel<<<GB12, 512, 0, stream>>>(mean1, xb, w1b, b1, w2b, y2l, y2r);
  agg_nr128<<<AGB, 256, 0, stream>>>(y2l, y2r, b2, row_ptr, col, inv_deg, h2);

  // ---- Layer 3 ----
  mfma_gemm<128, 128, true><<<GB12, 512, 0, stream>>>(h2, w3b, y3l, y3r);
  agg_nr64<<<AGB, 256, 0, stream>>>(y3l, y3r, b3, row_ptr, col, inv_deg, h3f);

  // ---- FC + softmax ----
  fc_partial_kernel<<<FC_BLOCKS, 256, 0, stream>>>(fcW, h3f, partial);
  fc_final_kernel<<<1, 256, 0, stream>>>(partial, fcb, out5);
}